// Round 11
// baseline (1185.509 us; speedup 1.0000x reference)
//
#include <hip/hip_runtime.h>
#include <cstdint>
#include <cstddef>

// Problem constants
#define SEQL   256
#define NBATCH 64
#define HDIM   512
#define ZDIM   2048   // 4*OUT
#define KDIM   1536   // in_dim

typedef __attribute__((ext_vector_type(8))) short short8;
typedef __attribute__((ext_vector_type(4))) float f32x4;
typedef __attribute__((ext_vector_type(2))) float f32x2;
typedef __attribute__((ext_vector_type(4))) float f4v;
typedef __attribute__((ext_vector_type(4))) unsigned uint4v;
typedef unsigned long long ull;

static __device__ __forceinline__ unsigned short f2bf(float f) {
  union { float f; unsigned u; } v; v.f = f;
  unsigned u = v.u;
  unsigned r = (u + 0x7FFFu + ((u >> 16) & 1u)) >> 16;   // RNE
  return (unsigned short)r;
}
static __device__ __forceinline__ float bf2f(unsigned short s) {
  union { unsigned u; float f; } v; v.u = ((unsigned)s) << 16; return v.f;
}
static __device__ __forceinline__ float sigm(float x)  { return 1.f / (1.f + __expf(-x)); }
static __device__ __forceinline__ float tanh_f(float x){ return 1.f - 2.f / (__expf(2.f * x) + 1.f); }

static __device__ __forceinline__ void gl_lds16(const void* g, void* l) {
  __builtin_amdgcn_global_load_lds((const __attribute__((address_space(1))) unsigned int*)g,
                                   (__attribute__((address_space(3))) unsigned int*)l, 16, 0, 0);
}

// ---------------------------------------------------------------- prep kernels

// x (b,t,k) f32 -> Xb[r][k] bf16 with r = t*64 + b
__global__ __launch_bounds__(256) void k_convx(const float* __restrict__ x,
                                               unsigned short* __restrict__ Xb) {
  int i = blockIdx.x * 256 + threadIdx.x;
  int k8 = (i & 63) * 8;
  int r  = i >> 6;
  int b  = r & 63, t = r >> 6;
  const float* src = x + ((size_t)(b * SEQL + t) * HDIM + k8);
  f4v v0 = *(const f4v*)src;
  f4v v1 = *(const f4v*)(src + 4);
  short8 o;
#pragma unroll
  for (int j = 0; j < 4; ++j) o[j] = (short)f2bf(v0[j]);
#pragma unroll
  for (int j = 0; j < 4; ++j) o[4 + j] = (short)f2bf(v1[j]);
  *(short8*)(Xb + (size_t)r * HDIM + k8) = o;
}

// g (64,512) f32 -> bf16
__global__ __launch_bounds__(256) void k_convg(const float* __restrict__ g,
                                               unsigned short* __restrict__ gbf) {
  int i = blockIdx.x * 256 + threadIdx.x;
  int k8 = (i & 63) * 8;
  int row = i >> 6;
  const float* src = g + ((size_t)row * HDIM + k8);
  f4v v0 = *(const f4v*)src;
  f4v v1 = *(const f4v*)(src + 4);
  short8 o;
#pragma unroll
  for (int j = 0; j < 4; ++j) o[j] = (short)f2bf(v0[j]);
#pragma unroll
  for (int j = 0; j < 4; ++j) o[4 + j] = (short)f2bf(v1[j]);
  *(short8*)(gbf + (size_t)row * HDIM + k8) = o;
}

// W (1536,2048) f32 -> Wt (2048,1536) bf16 (transposed)
__global__ __launch_bounds__(256) void k_trans(const float* __restrict__ W,
                                               unsigned short* __restrict__ Wt) {
  __shared__ float tile[32][33];
  int tx = threadIdx.x & 31, ty = threadIdx.x >> 5;
  int n0 = blockIdx.x * 32;
  int j0 = blockIdx.y * 32;
#pragma unroll
  for (int jj = 0; jj < 4; ++jj)
    tile[ty + jj * 8][tx] = W[(size_t)(j0 + ty + jj * 8) * ZDIM + n0 + tx];
  __syncthreads();
#pragma unroll
  for (int jj = 0; jj < 4; ++jj)
    Wt[(size_t)(n0 + ty + jj * 8) * KDIM + j0 + tx] = f2bf(tile[tx][ty + jj * 8]);
}

// gbuf[64][2048] = g @ Wg + bias
__global__ __launch_bounds__(256) void k_gb(const unsigned short* __restrict__ gbf,
                                            const unsigned short* __restrict__ Wt,
                                            const float* __restrict__ bias,
                                            float* __restrict__ gbuf) {
  int tid = threadIdx.x, l = tid & 63, w = tid >> 6;
  int n0 = blockIdx.x * 64 + w * 16;
  f32x4 acc[4] = {};
#pragma unroll
  for (int kb = 0; kb < 16; ++kb) {
    short8 bfr = *(const short8*)((const char*)Wt + (size_t)(n0 + (l & 15)) * 3072
                                  + 2048 + kb * 64 + (l >> 4) * 16);
#pragma unroll
    for (int mi = 0; mi < 4; ++mi) {
      short8 afr = *(const short8*)((const char*)gbf + (size_t)(mi * 16 + (l & 15)) * 1024
                                    + kb * 64 + (l >> 4) * 16);
      acc[mi] = __builtin_amdgcn_mfma_f32_16x16x32_bf16(afr, bfr, acc[mi], 0, 0, 0);
    }
  }
  int r0 = (l >> 4) * 4, cq = l & 15;
#pragma unroll
  for (int mi = 0; mi < 4; ++mi)
#pragma unroll
    for (int reg = 0; reg < 4; ++reg) {
      int row = mi * 16 + r0 + reg, col = n0 + cq;
      gbuf[(size_t)row * ZDIM + col] = acc[mi][reg] + bias[col];
    }
}

// ------------------------------------------------- phase-1 GEMM: zpre = Xb @ Wx^T + gbuf
__global__ __launch_bounds__(256, 2) void k_gemm_p1(const unsigned short* __restrict__ Xb,
                                                    const unsigned short* __restrict__ Wt,
                                                    const float* __restrict__ gbuf,
                                                    unsigned short* __restrict__ zpre) {
  __shared__ unsigned char sm[32768];
  int tm = blockIdx.x, tn = blockIdx.y;
  int tid = threadIdx.x, l = tid & 63, w = tid >> 6;
  int m0w = (w & 1) * 64, n0w = (w >> 1) * 64;
  f32x4 acc[4][4] = {};

  for (int k0 = 0; k0 < HDIM; k0 += 64) {
#pragma unroll
    for (int j = 0; j < 8; ++j) {
      int c = j * 4 + w;
      int lane_row = l >> 3;
      int kb = (l & 7) * 16;
      const char* gsrc;
      if (c < 16) {
        int row = c * 8 + lane_row;
        gsrc = (const char*)Xb + (size_t)(tm * 128 + row) * 1024 + k0 * 2 + kb;
      } else {
        int row = (c - 16) * 8 + lane_row;
        gsrc = (const char*)Wt + (size_t)(tn * 128 + row) * 3072 + k0 * 2 + kb;
      }
      gl_lds16(gsrc, (char*)sm + c * 1024);
    }
    __syncthreads();

#pragma unroll
    for (int kk = 0; kk < 64; kk += 32) {
      short8 af[4], bf[4];
#pragma unroll
      for (int mi = 0; mi < 4; ++mi)
        af[mi] = *(const short8*)((const char*)sm + (size_t)(m0w + mi * 16 + (l & 15)) * 128
                                  + (kk + (l >> 4) * 8) * 2);
#pragma unroll
      for (int ni = 0; ni < 4; ++ni)
        bf[ni] = *(const short8*)((const char*)sm + 16384 + (size_t)(n0w + ni * 16 + (l & 15)) * 128
                                  + (kk + (l >> 4) * 8) * 2);
#pragma unroll
      for (int mi = 0; mi < 4; ++mi)
#pragma unroll
        for (int ni = 0; ni < 4; ++ni)
          acc[mi][ni] = __builtin_amdgcn_mfma_f32_16x16x32_bf16(af[mi], bf[ni], acc[mi][ni], 0, 0, 0);
    }
    __syncthreads();
  }

  int r0 = (l >> 4) * 4, cq = l & 15;
#pragma unroll
  for (int mi = 0; mi < 4; ++mi)
#pragma unroll
    for (int ni = 0; ni < 4; ++ni) {
      int col = tn * 128 + n0w + ni * 16 + cq;
#pragma unroll
      for (int reg = 0; reg < 4; ++reg) {
        int row = tm * 128 + m0w + mi * 16 + r0 + reg;
        float v = acc[mi][ni][reg] + gbuf[(size_t)(row & 63) * ZDIM + col];
        zpre[(size_t)row * ZDIM + col] = f2bf(v);
      }
    }
}

// ---------------------------------------------------------- persistent recurrence
// 128 wgs; mapping gid = bid&7 (dir,band sync group), cg = bid>>3 (16 colgroups).
// Packets: 8B {u32 data = 2xbf16 exact, u32 stamp = step}; stamp-match = arrival.
// R11 store order: sc0 FIRST (fast local-L2 publish; same-address ordering no
// longer delays it behind the L3 store), then sc0 sc1 (L3 truth, cross-XCD
// liveness). Consumers poll sc0 (local L2, ~300ns when the bid%8->XCD mapping
// holds -- proven by R10's FETCH drop); L3 fallback only every 8th attempt for
// liveness when mapping is broken. CORRECTNESS IS SCOPE-INDEPENDENT: stamp s is
// written exactly once per address; a matching stamp implies correct data no
// matter which cache served it; stale lines only show old stamps (-> retry).

__global__ __launch_bounds__(256, 1) void k_rec(const unsigned short* __restrict__ Wt,
                                                const unsigned short* __restrict__ zpre,
                                                ull* __restrict__ hbuf8,   // [2][2][64][256] packets
                                                float* __restrict__ out,
                                                float* __restrict__ hstate,
                                                float* __restrict__ cstate) {
  __shared__ short lwh[4 * 32 * 512];         // 128KB: [gate][col(32)][k(512)] bf16, XOR-swizzled
  __shared__ unsigned char As[16 * 1024];     // 16KB: A tile [row(16)][k(512)] bf16, XOR-swizzled
  __shared__ float zbuf[4][16][33];           // 8.4KB (+1 pad col)

  const int tid = threadIdx.x, l = tid & 63, gi = tid >> 6;   // wave = gate (i,f,o,u)
  const int bid = blockIdx.x;
  const int gid = bid & 7, cg = bid >> 3;     // group-per-XCD heuristic mapping
  const int dir = gid >> 2, bg = gid & 3;
  const int hc0 = cg * 32;

  // stage Wh slice (gate gi, cols hc0..hc0+31) into LDS; per-wave private region.
#pragma unroll
  for (int col = 0; col < 32; ++col) {
    int kbs = l * 16;
    int kbyte = kbs ^ ((col & 7) << 4);
    short8 v = *(const short8*)((const char*)Wt
                + (size_t)(gi * 512 + hc0 + col) * 3072 + 1024 + kbyte);
    *(short8*)((char*)lwh + gi * 32768 + col * 1024 + kbs) = v;
  }

  const int r = tid >> 4, q = tid & 15;   // gate-math: row r (0..15), cols 2q, 2q+1
  float c0 = 0.f, c1 = 0.f, h0 = 0.f, h1 = 0.f;

  // prefetch zpre for first step (cached loads; L2 stays warm)
  int t = dir ? (SEQL - 1) : 0;
  unsigned zp[4];
  {
    const char* zb = (const char*)zpre
        + (((size_t)t * 64 + bg * 16 + r) * ZDIM + hc0 + 2 * q) * 2;
#pragma unroll
    for (int gg = 0; gg < 4; ++gg) zp[gg] = *(const unsigned*)(zb + gg * 1024);
  }

  // producer packet index: [dir*64 + bg*16 + r][cg*16 + q]
  const size_t p_idx = ((size_t)(dir * 64 + bg * 16 + r)) * 256 + cg * 16 + q;
  // consumer lane layout: rows prow=l>>3 and prow+8; packet pair (l&7)*2,(+1) per chunk
  const int prow = l >> 3;
  const int cp8 = (l & 7) * 8;            // LDS byte offset of the 2-packet data pair

  for (int s = 0; s < SEQL; ++s) {
    f32x4 acc0 = {0.f, 0.f, 0.f, 0.f}, acc1 = {0.f, 0.f, 0.f, 0.f};

    if (s) {
      const unsigned e = (unsigned)(s - 1);
      const char* rg = (const char*)hbuf8 + (size_t)((s - 1) & 1) * 262144;
      const char* b0 = rg + (size_t)(dir * 64 + bg * 16 + prow) * 2048
                          + gi * 512 + (l & 7) * 16;
      const char* b1 = b0 + 16384;        // +8 rows
      uint4v A0, A1, B0, B1, C0, C1, D0, D1;
      int gd = 0; bool ok;
#define LQ2(OFF, SC, V0, V1) \
      asm volatile("global_load_dwordx4 %0, %2, off offset:" OFF " " SC "\n\t" \
                   "global_load_dwordx4 %1, %3, off offset:" OFF " " SC \
                   : "=&v"(V0), "=&v"(V1) : "v"(b0), "v"(b1) : "memory")
      do {
        if ((gd & 7) != 7) {              // fast local-L2 attempts (healthy path)
          LQ2("0",   "sc0", A0, A1);
          LQ2("128", "sc0", B0, B1);
          LQ2("256", "sc0", C0, C1);
          LQ2("384", "sc0", D0, D1);
        } else {                          // rare guaranteed-live L3 attempt
          LQ2("0",   "sc0 sc1", A0, A1);
          LQ2("128", "sc0 sc1", B0, B1);
          LQ2("256", "sc0 sc1", C0, C1);
          LQ2("384", "sc0 sc1", D0, D1);
        }
        asm volatile("s_waitcnt vmcnt(0)"
          : "+v"(A0), "+v"(A1), "+v"(B0), "+v"(B1),
            "+v"(C0), "+v"(C1), "+v"(D0), "+v"(D1) :: "memory");
        __builtin_amdgcn_sched_barrier(0);
        ok = (A0[1] == e) && (A0[3] == e) && (A1[1] == e) && (A1[3] == e)
          && (B0[1] == e) && (B0[3] == e) && (B1[1] == e) && (B1[3] == e)
          && (C0[1] == e) && (C0[3] == e) && (C1[1] == e) && (C1[3] == e)
          && (D0[1] == e) && (D0[3] == e) && (D1[1] == e) && (D1[3] == e);
      } while (!__all(ok) && ++gd < (1 << 18));   // hang guard (never in practice)
#undef LQ2

      // strip stamps -> LDS (8B per write; XOR-swizzled rows)
      {
        const int r0b = prow * 1024 + gi * 256 + cp8;
        const int r1b = (prow + 8) * 1024 + gi * 256 + cp8;
        const int x = (prow & 7) << 4;
#define PKD(V) ((ull)V[0] | ((ull)V[2] << 32))
        *(ull*)(As + ((r0b +   0) ^ x)) = PKD(A0);
        *(ull*)(As + ((r1b +   0) ^ x)) = PKD(A1);
        *(ull*)(As + ((r0b +  64) ^ x)) = PKD(B0);
        *(ull*)(As + ((r1b +  64) ^ x)) = PKD(B1);
        *(ull*)(As + ((r0b + 128) ^ x)) = PKD(C0);
        *(ull*)(As + ((r1b + 128) ^ x)) = PKD(C1);
        *(ull*)(As + ((r0b + 192) ^ x)) = PKD(D0);
        *(ull*)(As + ((r1b + 192) ^ x)) = PKD(D1);
#undef PKD
      }
    }
    __syncthreads();   // A tile ready in LDS (s==0: nothing, acc stays 0)

    if (s) {
#pragma unroll
      for (int kb = 0; kb < 16; ++kb) {
        int arow = l & 15;
        int abyte = (arow * 1024 + kb * 64 + (l >> 4) * 16) ^ ((arow & 7) << 4);
        short8 a = *(const short8*)(As + abyte);
        int kfrag = kb * 64 + (l >> 4) * 16;
        int kbyte = kfrag ^ ((l & 7) << 4);
        short8 b0v = *(const short8*)((const char*)lwh + gi * 32768 + (size_t)(l & 15) * 1024 + kbyte);
        short8 b1v = *(const short8*)((const char*)lwh + gi * 32768 + (size_t)(16 + (l & 15)) * 1024 + kbyte);
        acc0 = __builtin_amdgcn_mfma_f32_16x16x32_bf16(a, b0v, acc0, 0, 0, 0);
        acc1 = __builtin_amdgcn_mfma_f32_16x16x32_bf16(a, b1v, acc1, 0, 0, 0);
      }
    }

    {
      int col = l & 15, row0 = (l >> 4) * 4;
#pragma unroll
      for (int reg = 0; reg < 4; ++reg) {
        zbuf[gi][row0 + reg][col]      = acc0[reg];
        zbuf[gi][row0 + reg][col + 16] = acc1[reg];
      }
    }
    __syncthreads();   // zbuf handoff

    // gate math: thread owns (row r, cols 2q, 2q+1)
    float zi0 = zbuf[0][r][2 * q]     + bf2f((unsigned short)(zp[0] & 0xffffu));
    float zi1 = zbuf[0][r][2 * q + 1] + bf2f((unsigned short)(zp[0] >> 16));
    float zf0 = zbuf[1][r][2 * q]     + bf2f((unsigned short)(zp[1] & 0xffffu));
    float zf1 = zbuf[1][r][2 * q + 1] + bf2f((unsigned short)(zp[1] >> 16));
    float zo0 = zbuf[2][r][2 * q]     + bf2f((unsigned short)(zp[2] & 0xffffu));
    float zo1 = zbuf[2][r][2 * q + 1] + bf2f((unsigned short)(zp[2] >> 16));
    float zu0 = zbuf[3][r][2 * q]     + bf2f((unsigned short)(zp[3] & 0xffffu));
    float zu1 = zbuf[3][r][2 * q + 1] + bf2f((unsigned short)(zp[3] >> 16));

    c0 = sigm(zf0) * c0 + sigm(zi0) * tanh_f(zu0);
    h0 = sigm(zo0) * tanh_f(c0);
    c1 = sigm(zf1) * c1 + sigm(zi1) * tanh_f(zu1);
    h1 = sigm(zo1) * tanh_f(c1);

    // publish h packet {2xbf16 exact, stamp = s}: sc0 first (fast local L2),
    // then sc0 sc1 (L3 truth). Same payload -> any interleaving correct.
    {
      unsigned hd = (unsigned)f2bf(h0) | ((unsigned)f2bf(h1) << 16);
      ull pv = (ull)hd | ((ull)(unsigned)s << 32);
      ull* ps = hbuf8 + (size_t)(s & 1) * 32768 + p_idx;
      asm volatile("global_store_dwordx2 %0, %1, off sc0"     :: "v"(ps), "v"(pv) : "memory");
      asm volatile("global_store_dwordx2 %0, %1, off sc0 sc1" :: "v"(ps), "v"(pv) : "memory");
    }

    // off-critical-path: out store + next zpre prefetch
    {
      f32x2 ho; ho.x = h0; ho.y = h1;
      __builtin_nontemporal_store(ho, reinterpret_cast<f32x2*>(
          out + ((size_t)(bg * 16 + r) * SEQL + t) * 1024 + dir * 512 + hc0 + 2 * q));
    }
    if (s + 1 < SEQL) {
      t = dir ? (SEQL - 2 - s) : (s + 1);
      const char* zb = (const char*)zpre
          + (((size_t)t * 64 + bg * 16 + r) * ZDIM + hc0 + 2 * q) * 2;
#pragma unroll
      for (int gg = 0; gg < 4; ++gg) zp[gg] = *(const unsigned*)(zb + gg * 1024);
    }
  }

  // final states
  {
    size_t st = (size_t)(bg * 16 + r) * 1024 + dir * 512 + hc0 + 2 * q;
    f32x2 hv; hv.x = h0; hv.y = h1;
    f32x2 cv2; cv2.x = c0; cv2.y = c1;
    __builtin_nontemporal_store(hv, reinterpret_cast<f32x2*>(hstate + st));
    __builtin_nontemporal_store(cv2, reinterpret_cast<f32x2*>(cstate + st));
  }
}

// ---------------------------------------------------------------------- launch

extern "C" void kernel_launch(void* const* d_in, const int* in_sizes, int n_in,
                              void* d_out, int out_size, void* d_ws, size_t ws_size,
                              hipStream_t stream) {
  const float* x    = (const float*)d_in[0];
  const float* g    = (const float*)d_in[1];
  const float* W    = (const float*)d_in[2];
  const float* bias = (const float*)d_in[3];
  float* out = (float*)d_out;
  float* hstate = out + (size_t)16777216;            // 64*256*1024
  float* cstate = out + (size_t)16842752;            // + 64*1024

  char* ws = (char*)d_ws;
  ull* hbuf8 = (ull*)(ws + 0);                                // 512KB: 2 regions x [2][64][256] x 8B
  unsigned short* Xb   = (unsigned short*)(ws + 524288);      // 16MB
  unsigned short* Wt   = (unsigned short*)(ws + 17301504);    // 6MB
  unsigned short* gbf  = (unsigned short*)(ws + 23592960);    // 64KB
  float*          gbuf = (float*)(ws + 23658496);             // 512KB
  unsigned short* zpre = (unsigned short*)(ws + 24182784);    // 64MB

  // pre-stamp both h regions with 0xFF (matches no expected stamp; also cleans
  // previous replay's stamps -- harness doesn't re-poison ws between replays).
  hipMemsetAsync((void*)hbuf8, 0xFF, 524288, stream);

  k_convx<<<4096, 256, 0, stream>>>(x, Xb);
  k_convg<<<16, 256, 0, stream>>>(g, gbf);
  k_trans<<<dim3(64, 48), 256, 0, stream>>>(W, Wt);
  k_gb<<<32, 256, 0, stream>>>(gbf, Wt, bias, gbuf);
  k_gemm_p1<<<dim3(128, 16), 256, 0, stream>>>(Xb, Wt, gbuf, zpre);
  k_rec<<<128, 256, 0, stream>>>(Wt, zpre, hbuf8, out, hstate, cstate);
}

// Round 12
// 868.356 us; speedup vs baseline: 1.3652x; 1.3652x over previous
//
#include <hip/hip_runtime.h>
#include <cstdint>
#include <cstddef>

// Problem constants
#define SEQL   256
#define NBATCH 64
#define HDIM   512
#define ZDIM   2048   // 4*OUT
#define KDIM   1536   // in_dim

typedef __attribute__((ext_vector_type(8))) short short8;
typedef __attribute__((ext_vector_type(4))) float f32x4;
typedef __attribute__((ext_vector_type(2))) float f32x2;
typedef __attribute__((ext_vector_type(4))) float f4v;
typedef unsigned long long ull;

static __device__ __forceinline__ unsigned short f2bf(float f) {
  union { float f; unsigned u; } v; v.f = f;
  unsigned u = v.u;
  unsigned r = (u + 0x7FFFu + ((u >> 16) & 1u)) >> 16;   // RNE
  return (unsigned short)r;
}
static __device__ __forceinline__ float bf2f(unsigned short s) {
  union { unsigned u; float f; } v; v.u = ((unsigned)s) << 16; return v.f;
}
static __device__ __forceinline__ float sigm(float x)  { return 1.f / (1.f + __expf(-x)); }
static __device__ __forceinline__ float tanh_f(float x){ return 1.f - 2.f / (__expf(2.f * x) + 1.f); }

static __device__ __forceinline__ void gl_lds16(const void* g, void* l) {
  __builtin_amdgcn_global_load_lds((const __attribute__((address_space(1))) unsigned int*)g,
                                   (__attribute__((address_space(3))) unsigned int*)l, 16, 0, 0);
}

// ---------------------------------------------------------------- prep kernels

// x (b,t,k) f32 -> Xb[r][k] bf16 with r = t*64 + b
__global__ __launch_bounds__(256) void k_convx(const float* __restrict__ x,
                                               unsigned short* __restrict__ Xb) {
  int i = blockIdx.x * 256 + threadIdx.x;
  int k8 = (i & 63) * 8;
  int r  = i >> 6;
  int b  = r & 63, t = r >> 6;
  const float* src = x + ((size_t)(b * SEQL + t) * HDIM + k8);
  f4v v0 = *(const f4v*)src;
  f4v v1 = *(const f4v*)(src + 4);
  short8 o;
#pragma unroll
  for (int j = 0; j < 4; ++j) o[j] = (short)f2bf(v0[j]);
#pragma unroll
  for (int j = 0; j < 4; ++j) o[4 + j] = (short)f2bf(v1[j]);
  *(short8*)(Xb + (size_t)r * HDIM + k8) = o;
}

// g (64,512) f32 -> bf16
__global__ __launch_bounds__(256) void k_convg(const float* __restrict__ g,
                                               unsigned short* __restrict__ gbf) {
  int i = blockIdx.x * 256 + threadIdx.x;
  int k8 = (i & 63) * 8;
  int row = i >> 6;
  const float* src = g + ((size_t)row * HDIM + k8);
  f4v v0 = *(const f4v*)src;
  f4v v1 = *(const f4v*)(src + 4);
  short8 o;
#pragma unroll
  for (int j = 0; j < 4; ++j) o[j] = (short)f2bf(v0[j]);
#pragma unroll
  for (int j = 0; j < 4; ++j) o[4 + j] = (short)f2bf(v1[j]);
  *(short8*)(gbf + (size_t)row * HDIM + k8) = o;
}

// W (1536,2048) f32 -> Wt (2048,1536) bf16 (transposed)
__global__ __launch_bounds__(256) void k_trans(const float* __restrict__ W,
                                               unsigned short* __restrict__ Wt) {
  __shared__ float tile[32][33];
  int tx = threadIdx.x & 31, ty = threadIdx.x >> 5;
  int n0 = blockIdx.x * 32;
  int j0 = blockIdx.y * 32;
#pragma unroll
  for (int jj = 0; jj < 4; ++jj)
    tile[ty + jj * 8][tx] = W[(size_t)(j0 + ty + jj * 8) * ZDIM + n0 + tx];
  __syncthreads();
#pragma unroll
  for (int jj = 0; jj < 4; ++jj)
    Wt[(size_t)(n0 + ty + jj * 8) * KDIM + j0 + tx] = f2bf(tile[tx][ty + jj * 8]);
}

// gbuf[64][2048] = g @ Wg + bias
__global__ __launch_bounds__(256) void k_gb(const unsigned short* __restrict__ gbf,
                                            const unsigned short* __restrict__ Wt,
                                            const float* __restrict__ bias,
                                            float* __restrict__ gbuf) {
  int tid = threadIdx.x, l = tid & 63, w = tid >> 6;
  int n0 = blockIdx.x * 64 + w * 16;
  f32x4 acc[4] = {};
#pragma unroll
  for (int kb = 0; kb < 16; ++kb) {
    short8 bfr = *(const short8*)((const char*)Wt + (size_t)(n0 + (l & 15)) * 3072
                                  + 2048 + kb * 64 + (l >> 4) * 16);
#pragma unroll
    for (int mi = 0; mi < 4; ++mi) {
      short8 afr = *(const short8*)((const char*)gbf + (size_t)(mi * 16 + (l & 15)) * 1024
                                    + kb * 64 + (l >> 4) * 16);
      acc[mi] = __builtin_amdgcn_mfma_f32_16x16x32_bf16(afr, bfr, acc[mi], 0, 0, 0);
    }
  }
  int r0 = (l >> 4) * 4, cq = l & 15;
#pragma unroll
  for (int mi = 0; mi < 4; ++mi)
#pragma unroll
    for (int reg = 0; reg < 4; ++reg) {
      int row = mi * 16 + r0 + reg, col = n0 + cq;
      gbuf[(size_t)row * ZDIM + col] = acc[mi][reg] + bias[col];
    }
}

// ------------------------------------------------- phase-1 GEMM: zpre = Xb @ Wx^T + gbuf
__global__ __launch_bounds__(256, 2) void k_gemm_p1(const unsigned short* __restrict__ Xb,
                                                    const unsigned short* __restrict__ Wt,
                                                    const float* __restrict__ gbuf,
                                                    unsigned short* __restrict__ zpre) {
  __shared__ unsigned char sm[32768];
  int tm = blockIdx.x, tn = blockIdx.y;
  int tid = threadIdx.x, l = tid & 63, w = tid >> 6;
  int m0w = (w & 1) * 64, n0w = (w >> 1) * 64;
  f32x4 acc[4][4] = {};

  for (int k0 = 0; k0 < HDIM; k0 += 64) {
#pragma unroll
    for (int j = 0; j < 8; ++j) {
      int c = j * 4 + w;
      int lane_row = l >> 3;
      int kb = (l & 7) * 16;
      const char* gsrc;
      if (c < 16) {
        int row = c * 8 + lane_row;
        gsrc = (const char*)Xb + (size_t)(tm * 128 + row) * 1024 + k0 * 2 + kb;
      } else {
        int row = (c - 16) * 8 + lane_row;
        gsrc = (const char*)Wt + (size_t)(tn * 128 + row) * 3072 + k0 * 2 + kb;
      }
      gl_lds16(gsrc, (char*)sm + c * 1024);
    }
    __syncthreads();

#pragma unroll
    for (int kk = 0; kk < 64; kk += 32) {
      short8 af[4], bf[4];
#pragma unroll
      for (int mi = 0; mi < 4; ++mi)
        af[mi] = *(const short8*)((const char*)sm + (size_t)(m0w + mi * 16 + (l & 15)) * 128
                                  + (kk + (l >> 4) * 8) * 2);
#pragma unroll
      for (int ni = 0; ni < 4; ++ni)
        bf[ni] = *(const short8*)((const char*)sm + 16384 + (size_t)(n0w + ni * 16 + (l & 15)) * 128
                                  + (kk + (l >> 4) * 8) * 2);
#pragma unroll
      for (int mi = 0; mi < 4; ++mi)
#pragma unroll
        for (int ni = 0; ni < 4; ++ni)
          acc[mi][ni] = __builtin_amdgcn_mfma_f32_16x16x32_bf16(af[mi], bf[ni], acc[mi][ni], 0, 0, 0);
    }
    __syncthreads();
  }

  int r0 = (l >> 4) * 4, cq = l & 15;
#pragma unroll
  for (int mi = 0; mi < 4; ++mi)
#pragma unroll
    for (int ni = 0; ni < 4; ++ni) {
      int col = tn * 128 + n0w + ni * 16 + cq;
#pragma unroll
      for (int reg = 0; reg < 4; ++reg) {
        int row = tm * 128 + m0w + mi * 16 + r0 + reg;
        float v = acc[mi][ni][reg] + gbuf[(size_t)(row & 63) * ZDIM + col];
        zpre[(size_t)row * ZDIM + col] = f2bf(v);
      }
    }
}

// ---------------------------------------------------------- persistent recurrence
// 128 wgs = dir(2) x band(4; 16 rows) x colgroup(16; 32 h-cols). 4 waves = 4 gates.
// R8 semantics restored: all h exchange via relaxed SYSTEM-scope 8B atomic
// packets {u32 data = 2xbf16 exact, u32 stamp = step}; stamp-match = arrival
// (one coherence-point round trip, no fences, no flags). R12 adds DEPTH-2
// PIPELINED POLLING: two register sets A/B alternate -- issue B, check A
// (B's loads stay in flight), issue A, check B. Detection granularity ~RT/2
// instead of RT. Intrinsic loads keep the compiler tracking registers and
// waitcnts (no inline-asm clobber hazard); sched_barrier(0) pins issue-before-
// check order; per-path strip macros avoid runtime-indexed arrays (scratch).

__global__ __launch_bounds__(256, 1) void k_rec(const unsigned short* __restrict__ Wt,
                                                const unsigned short* __restrict__ zpre,
                                                ull* __restrict__ hbuf8,   // [2][2][64][256] packets
                                                float* __restrict__ out,
                                                float* __restrict__ hstate,
                                                float* __restrict__ cstate) {
  __shared__ short lwh[4 * 32 * 512];         // 128KB: [gate][col(32)][k(512)] bf16, XOR-swizzled
  __shared__ unsigned char As[16 * 1024];     // 16KB: A tile [row(16)][k(512)] bf16, XOR-swizzled
  __shared__ float zbuf[4][16][33];           // 8.4KB (+1 pad col)

  const int tid = threadIdx.x, l = tid & 63, gi = tid >> 6;   // wave = gate (i,f,o,u)
  const int bid = blockIdx.x;
  const int cg = bid & 15, gid = bid >> 4, dir = gid >> 2, bg = gid & 3;
  const int hc0 = cg * 32;

  // stage Wh slice (gate gi, cols hc0..hc0+31) into LDS; per-wave private region.
#pragma unroll
  for (int col = 0; col < 32; ++col) {
    int kbs = l * 16;
    int kbyte = kbs ^ ((col & 7) << 4);
    short8 v = *(const short8*)((const char*)Wt
                + (size_t)(gi * 512 + hc0 + col) * 3072 + 1024 + kbyte);
    *(short8*)((char*)lwh + gi * 32768 + col * 1024 + kbs) = v;
  }

  const int r = tid >> 4, q = tid & 15;   // gate-math: row r (0..15), cols 2q, 2q+1
  float c0 = 0.f, c1 = 0.f, h0 = 0.f, h1 = 0.f;

  // prefetch zpre for first step (cached loads; L2 stays warm)
  int t = dir ? (SEQL - 1) : 0;
  unsigned zp[4];
  {
    const char* zb = (const char*)zpre
        + (((size_t)t * 64 + bg * 16 + r) * ZDIM + hc0 + 2 * q) * 2;
#pragma unroll
    for (int gg = 0; gg < 4; ++gg) zp[gg] = *(const unsigned*)(zb + gg * 1024);
  }

  // producer packet index: [dir*64 + bg*16 + r][cg*16 + q]
  const size_t p_idx = ((size_t)(dir * 64 + bg * 16 + r)) * 256 + cg * 16 + q;
  // consumer: wave gi polls k-chunks kb = gi*4..gi*4+3; lane handles
  // rows it*4 + (l>>4), col-pair (l&15) of each chunk.
  const int c_row = l >> 4, c_cp = l & 15;

// load one full poll set (16 x 8B relaxed system-scope atomic loads)
#define LOADSET(V) \
  _Pragma("unroll") \
  for (int it_ = 0; it_ < 4; ++it_) \
    _Pragma("unroll") \
    for (int kk_ = 0; kk_ < 4; ++kk_) \
      V[it_ * 4 + kk_] = __hip_atomic_load( \
          hb + ((size_t)(dir * 64 + bg * 16 + it_ * 4 + c_row)) * 256 \
             + (gi * 4 + kk_) * 16 + c_cp, \
          __ATOMIC_RELAXED, __HIP_MEMORY_SCOPE_SYSTEM)

// strip stamps of a set -> LDS (XOR-swizzled rows)
#define STRIPSET(V) \
  _Pragma("unroll") \
  for (int it_ = 0; it_ < 4; ++it_) \
    _Pragma("unroll") \
    for (int kk_ = 0; kk_ < 4; ++kk_) { \
      int row_ = it_ * 4 + c_row; \
      int byte_ = (row_ * 1024 + (gi * 4 + kk_) * 64 + c_cp * 4) ^ ((row_ & 7) << 4); \
      *(unsigned*)(As + byte_) = (unsigned)V[it_ * 4 + kk_]; }

  for (int s = 0; s < SEQL; ++s) {
    f32x4 acc0 = {0.f, 0.f, 0.f, 0.f}, acc1 = {0.f, 0.f, 0.f, 0.f};

    if (s) {
      const unsigned e = (unsigned)(s - 1);
      const ull* hb = hbuf8 + (size_t)((s - 1) & 1) * 32768;
      ull va[16], vb[16];
      int gd = 0;

      LOADSET(va);                       // prime set A
      for (;;) {
        LOADSET(vb);                     // B in flight while we check A
        __builtin_amdgcn_sched_barrier(0);
        bool ok = true;
#pragma unroll
        for (int i = 0; i < 16; ++i) ok = ok && ((unsigned)(va[i] >> 32) == e);
        if (__all(ok)) { STRIPSET(va); break; }

        LOADSET(va);                     // A in flight while we check B
        __builtin_amdgcn_sched_barrier(0);
        ok = true;
#pragma unroll
        for (int i = 0; i < 16; ++i) ok = ok && ((unsigned)(vb[i] >> 32) == e);
        if (__all(ok)) { STRIPSET(vb); break; }

        if (++gd > (1 << 17)) { STRIPSET(va); break; }   // hang guard
      }
    }
    __syncthreads();   // A tile ready in LDS (s==0: nothing, acc stays 0)

    if (s) {
#pragma unroll
      for (int kb = 0; kb < 16; ++kb) {
        int arow = l & 15;
        int abyte = (arow * 1024 + kb * 64 + (l >> 4) * 16) ^ ((arow & 7) << 4);
        short8 a = *(const short8*)(As + abyte);
        int kfrag = kb * 64 + (l >> 4) * 16;
        int kbyte = kfrag ^ ((l & 7) << 4);
        short8 b0 = *(const short8*)((const char*)lwh + gi * 32768 + (size_t)(l & 15) * 1024 + kbyte);
        short8 b1 = *(const short8*)((const char*)lwh + gi * 32768 + (size_t)(16 + (l & 15)) * 1024 + kbyte);
        acc0 = __builtin_amdgcn_mfma_f32_16x16x32_bf16(a, b0, acc0, 0, 0, 0);
        acc1 = __builtin_amdgcn_mfma_f32_16x16x32_bf16(a, b1, acc1, 0, 0, 0);
      }
    }

    {
      int col = l & 15, row0 = (l >> 4) * 4;
#pragma unroll
      for (int reg = 0; reg < 4; ++reg) {
        zbuf[gi][row0 + reg][col]      = acc0[reg];
        zbuf[gi][row0 + reg][col + 16] = acc1[reg];
      }
    }
    __syncthreads();   // zbuf handoff

    // gate math: thread owns (row r, cols 2q, 2q+1)
    float zi0 = zbuf[0][r][2 * q]     + bf2f((unsigned short)(zp[0] & 0xffffu));
    float zi1 = zbuf[0][r][2 * q + 1] + bf2f((unsigned short)(zp[0] >> 16));
    float zf0 = zbuf[1][r][2 * q]     + bf2f((unsigned short)(zp[1] & 0xffffu));
    float zf1 = zbuf[1][r][2 * q + 1] + bf2f((unsigned short)(zp[1] >> 16));
    float zo0 = zbuf[2][r][2 * q]     + bf2f((unsigned short)(zp[2] & 0xffffu));
    float zo1 = zbuf[2][r][2 * q + 1] + bf2f((unsigned short)(zp[2] >> 16));
    float zu0 = zbuf[3][r][2 * q]     + bf2f((unsigned short)(zp[3] & 0xffffu));
    float zu1 = zbuf[3][r][2 * q + 1] + bf2f((unsigned short)(zp[3] >> 16));

    c0 = sigm(zf0) * c0 + sigm(zi0) * tanh_f(zu0);
    h0 = sigm(zo0) * tanh_f(c0);
    c1 = sigm(zf1) * c1 + sigm(zi1) * tanh_f(zu1);
    h1 = sigm(zo1) * tanh_f(c1);

    // publish h packet: {2xbf16 exact, stamp = s} one 8B atomic store
    {
      unsigned hd = (unsigned)f2bf(h0) | ((unsigned)f2bf(h1) << 16);
      ull pv = (ull)hd | ((ull)(unsigned)s << 32);
      __hip_atomic_store(hbuf8 + (size_t)(s & 1) * 32768 + p_idx, pv,
                         __ATOMIC_RELAXED, __HIP_MEMORY_SCOPE_SYSTEM);
    }

    // off-critical-path: out store + next zpre prefetch
    {
      f32x2 ho; ho.x = h0; ho.y = h1;
      __builtin_nontemporal_store(ho, reinterpret_cast<f32x2*>(
          out + ((size_t)(bg * 16 + r) * SEQL + t) * 1024 + dir * 512 + hc0 + 2 * q));
    }
    if (s + 1 < SEQL) {
      t = dir ? (SEQL - 2 - s) : (s + 1);
      const char* zb = (const char*)zpre
          + (((size_t)t * 64 + bg * 16 + r) * ZDIM + hc0 + 2 * q) * 2;
#pragma unroll
      for (int gg = 0; gg < 4; ++gg) zp[gg] = *(const unsigned*)(zb + gg * 1024);
    }
  }

  // final states
  {
    size_t st = (size_t)(bg * 16 + r) * 1024 + dir * 512 + hc0 + 2 * q;
    f32x2 hv; hv.x = h0; hv.y = h1;
    f32x2 cv2; cv2.x = c0; cv2.y = c1;
    __builtin_nontemporal_store(hv, reinterpret_cast<f32x2*>(hstate + st));
    __builtin_nontemporal_store(cv2, reinterpret_cast<f32x2*>(cstate + st));
  }
#undef LOADSET
#undef STRIPSET
}

// ---------------------------------------------------------------------- launch

extern "C" void kernel_launch(void* const* d_in, const int* in_sizes, int n_in,
                              void* d_out, int out_size, void* d_ws, size_t ws_size,
                              hipStream_t stream) {
  const float* x    = (const float*)d_in[0];
  const float* g    = (const float*)d_in[1];
  const float* W    = (const float*)d_in[2];
  const float* bias = (const float*)d_in[3];
  float* out = (float*)d_out;
  float* hstate = out + (size_t)16777216;            // 64*256*1024
  float* cstate = out + (size_t)16842752;            // + 64*1024

  char* ws = (char*)d_ws;
  ull* hbuf8 = (ull*)(ws + 0);                                // 512KB: 2 regions x [2][64][256] x 8B
  unsigned short* Xb   = (unsigned short*)(ws + 524288);      // 16MB
  unsigned short* Wt   = (unsigned short*)(ws + 17301504);    // 6MB
  unsigned short* gbf  = (unsigned short*)(ws + 23592960);    // 64KB
  float*          gbuf = (float*)(ws + 23658496);             // 512KB
  unsigned short* zpre = (unsigned short*)(ws + 24182784);    // 64MB

  // pre-stamp both h regions with 0xFF (matches no expected stamp; also cleans
  // previous replay's stamps -- harness doesn't re-poison ws between replays).
  hipMemsetAsync((void*)hbuf8, 0xFF, 524288, stream);

  k_convx<<<4096, 256, 0, stream>>>(x, Xb);
  k_convg<<<16, 256, 0, stream>>>(g, gbf);
  k_trans<<<dim3(64, 48), 256, 0, stream>>>(W, Wt);
  k_gb<<<32, 256, 0, stream>>>(gbf, Wt, bias, gbuf);
  k_gemm_p1<<<dim3(128, 16), 256, 0, stream>>>(Xb, Wt, gbuf, zpre);
  k_rec<<<128, 256, 0, stream>>>(Wt, zpre, hbuf8, out, hstate, cstate);
}